// Round 1
// baseline (42324.194 us; speedup 1.0000x reference)
//
#include <hip/hip_runtime.h>
#include <math.h>

// Problem constants (from reference)
#define BATCH 2048
#define SEQ   80
#define EMBD  100
#define HU    512
#define G4    2048   // 4*HU

// Tiling
#define MT 64        // batch rows per block
#define UT 32        // units per block (each unit -> 4 gate columns)
#define KT 16        // K tile

// One fused LSTM step: z = A @ [W;U] + b, gates, c/h update.
// A = concat(x_t, h_prev) along K. For GATHER, x_t = emb[ids[:, t]].
// Each block: 64 rows x 32 units, computes all 4 gates per unit.
template <bool GATHER>
__global__ __launch_bounds__(256) void lstm_step(
    const int* __restrict__ ids, int t,
    const float* __restrict__ x,     // [BATCH, K1] when !GATHER
    const float* __restrict__ emb,   // [VOCAB, EMBD] when GATHER
    int K1,
    const float* __restrict__ W,     // [K1, 2048]
    const float* __restrict__ hprev, // [BATCH, 512]
    const float* __restrict__ U,     // [512, 2048]
    const float* __restrict__ bias,  // [2048]
    float* __restrict__ c,           // [BATCH, 512] in/out (thread-owned)
    float* __restrict__ hnew)        // [BATCH, 512] out
{
    const int tid = threadIdx.x;
    const int tx = tid & 15;   // unit group: units u0 + 2*tx + {0,1}
    const int ty = tid >> 4;   // row group:  rows  m0 + 4*ty + {0..3}
    const int m0 = blockIdx.y * MT;
    const int u0 = blockIdx.x * UT;

    __shared__ float As[KT][MT];       // [k][m]
    __shared__ float Bs[KT][4][UT];    // [k][gate][u]

    float acc[4][2][4];                // [row i][unit j][gate g]
    #pragma unroll
    for (int i = 0; i < 4; ++i)
        #pragma unroll
        for (int j = 0; j < 2; ++j)
            #pragma unroll
            for (int g = 0; g < 4; ++g) acc[i][j][g] = 0.f;

    const int Ktot = K1 + HU;
    const int ntiles = (Ktot + KT - 1) / KT;

    for (int kt = 0; kt < ntiles; ++kt) {
        const int k0 = kt * KT;

        // Load A tile: 64x16, 4 elems/thread, k-contiguous per row in global
        #pragma unroll
        for (int i = 0; i < 4; ++i) {
            int idx = tid + i * 256;      // 0..1023
            int m = idx >> 4;
            int k = idx & 15;
            int kk = k0 + k;
            int mg = m0 + m;
            float v = 0.f;
            if (kk < K1) {
                if (GATHER) v = emb[ids[mg * SEQ + t] * EMBD + kk];
                else        v = x[mg * K1 + kk];
            } else if (kk < Ktot) {
                v = hprev[mg * HU + (kk - K1)];
            }
            As[k][m] = v;
        }

        // Load B tile: 16 x (4 gates x 32 units), 8 elems/thread, u-contiguous
        #pragma unroll
        for (int i = 0; i < 8; ++i) {
            int idx = tid + i * 256;      // 0..2047
            int u = idx & 31;
            int g = (idx >> 5) & 3;
            int k = idx >> 7;
            int kk = k0 + k;
            int col = g * HU + u0 + u;
            float w = 0.f;
            if (kk < K1)       w = W[kk * G4 + col];
            else if (kk < Ktot) w = U[(kk - K1) * G4 + col];
            Bs[k][g][u] = w;
        }

        __syncthreads();

        #pragma unroll
        for (int k = 0; k < KT; ++k) {
            const float4 av = ((const float4*)&As[k][0])[ty];   // rows 4*ty..4*ty+3
            float a[4] = {av.x, av.y, av.z, av.w};
            #pragma unroll
            for (int g = 0; g < 4; ++g) {
                const float2 bv = ((const float2*)&Bs[k][g][0])[tx];
                #pragma unroll
                for (int i = 0; i < 4; ++i) {
                    acc[i][0][g] = fmaf(a[i], bv.x, acc[i][0][g]);
                    acc[i][1][g] = fmaf(a[i], bv.y, acc[i][1][g]);
                }
            }
        }

        __syncthreads();
    }

    // Epilogue: gates (Keras order i,f,g,o), c/h update
    #pragma unroll
    for (int i = 0; i < 4; ++i) {
        const int mg = m0 + ty * 4 + i;
        #pragma unroll
        for (int j = 0; j < 2; ++j) {
            const int ug = u0 + tx * 2 + j;
            const float zi = acc[i][j][0] + bias[ug];
            const float zf = acc[i][j][1] + bias[HU + ug];
            const float zg = acc[i][j][2] + bias[2 * HU + ug];
            const float zo = acc[i][j][3] + bias[3 * HU + ug];
            const float gi = 1.f / (1.f + expf(-zi));
            const float gf = 1.f / (1.f + expf(-zf));
            const float gg = tanhf(zg);
            const float go = 1.f / (1.f + expf(-zo));
            const float cn = gf * c[mg * HU + ug] + gi * gg;
            c[mg * HU + ug] = cn;
            hnew[mg * HU + ug] = go * tanhf(cn);
        }
    }
}

// out[b] = sigmoid(h2[b,:] @ Wd + bd); one wave per row
__global__ __launch_bounds__(256) void head_kernel(
    const float* __restrict__ h2, const float* __restrict__ Wd,
    const float* __restrict__ bd, float* __restrict__ out)
{
    const int b = blockIdx.x * 4 + (threadIdx.x >> 6);
    const int lane = threadIdx.x & 63;
    float s = 0.f;
    #pragma unroll
    for (int u = lane; u < HU; u += 64) s += h2[b * HU + u] * Wd[u];
    #pragma unroll
    for (int off = 32; off > 0; off >>= 1) s += __shfl_xor(s, off);
    if (lane == 0) out[b] = 1.f / (1.f + expf(-(s + bd[0])));
}

extern "C" void kernel_launch(void* const* d_in, const int* in_sizes, int n_in,
                              void* d_out, int out_size, void* d_ws, size_t ws_size,
                              hipStream_t stream)
{
    const int*   ids = (const int*)  d_in[0];
    const float* emb = (const float*)d_in[1];
    const float* W1  = (const float*)d_in[2];
    const float* U1  = (const float*)d_in[3];
    const float* b1  = (const float*)d_in[4];
    const float* W2  = (const float*)d_in[5];
    const float* U2  = (const float*)d_in[6];
    const float* b2  = (const float*)d_in[7];
    const float* Wd  = (const float*)d_in[8];
    const float* bd  = (const float*)d_in[9];
    float* out = (float*)d_out;

    // Workspace: [h1_0 | c1 | h2_0 | c2 | h1_1 | h2_1], each BATCH*HU fp32
    const size_t S = (size_t)BATCH * HU;
    float* ws  = (float*)d_ws;
    float* h1a = ws;
    float* c1  = h1a + S;
    float* h2a = c1 + S;
    float* c2  = h2a + S;
    float* h1b = c2 + S;
    float* h2b = h1b + S;

    // Zero-init h1_0, c1, h2_0, c2 (contiguous) every call — deterministic
    hipMemsetAsync(ws, 0, 4 * S * sizeof(float), stream);

    float* h1buf[2] = {h1a, h1b};
    float* h2buf[2] = {h2a, h2b};

    dim3 grid(HU / UT, BATCH / MT);   // (16, 32) = 512 blocks

    for (int t = 0; t < SEQ; ++t) {
        const int cur = t & 1, nxt = cur ^ 1;
        // Layer 1: x_t = emb[ids[:,t]] (K1=100), h = h1[cur] -> h1[nxt]
        lstm_step<true><<<grid, 256, 0, stream>>>(
            ids, t, nullptr, emb, EMBD, W1, h1buf[cur], U1, b1, c1, h1buf[nxt]);
        // Layer 2: x_t = h1[nxt] (K1=512), h = h2[cur] -> h2[nxt]
        lstm_step<false><<<grid, 256, 0, stream>>>(
            nullptr, 0, h1buf[nxt], nullptr, HU, W2, h2buf[cur], U2, b2, c2, h2buf[nxt]);
    }

    // Last h2 written is h2buf[(SEQ-1)&1 ^ 1] == h2buf[SEQ & 1] == h2buf[0]
    head_kernel<<<BATCH / 4, 256, 0, stream>>>(h2buf[SEQ & 1], Wd, bd, out);
}

// Round 2
// 6846.954 us; speedup vs baseline: 6.1815x; 6.1815x over previous
//
#include <hip/hip_runtime.h>
#include <hip/hip_bf16.h>
#include <math.h>

#define BATCH 2048
#define SEQ   80
#define EMBD  100
#define HU    512
#define NG    2048   // 4*HU

typedef short bf16x8 __attribute__((ext_vector_type(8)));
typedef float f32x4  __attribute__((ext_vector_type(4)));

#define AS1(p) ((const __attribute__((address_space(1))) void*)(p))
#define AS3(p) ((__attribute__((address_space(3))) void*)(p))

__device__ __forceinline__ float sigm(float x){ return 1.f/(1.f+__expf(-x)); }
__device__ __forceinline__ float tanha(float x){
    x = fminf(fmaxf(x,-15.f),15.f);
    float e = __expf(2.f*x);
    return (e-1.f)/(e+1.f);
}

// ---------------- prep kernels (run once per call, deterministic) ----------------

// emb fp32 [10000][100] -> embp bf16 [10000][128] (cols 100..127 zero)
__global__ __launch_bounds__(256) void prep_emb(const float* __restrict__ emb,
                                                __hip_bfloat16* __restrict__ embp)
{
    int idx = blockIdx.x*256 + threadIdx.x;   // 10000*128 total
    int row = idx >> 7, k = idx & 127;
    float v = (k < EMBD) ? emb[row*EMBD + k] : 0.f;
    embp[idx] = __float2bfloat16(v);
}

// Gate-interleaved transposed weights. n = u*4 + g, col_orig = g*512 + u.
// layer 0: wt1[n][k], K=640 : k<100 -> W1[k][col], 100..127 -> 0, 128..639 -> U1[k-128][col]
// layer 1: wt2[n][k], K=1024: k<512 -> W2[k][col], else U2[k-512][col]
__global__ __launch_bounds__(256) void prep_wt(
    const float* __restrict__ W1, const float* __restrict__ U1, const float* __restrict__ b1,
    const float* __restrict__ W2, const float* __restrict__ U2, const float* __restrict__ b2,
    __hip_bfloat16* __restrict__ wt1, __hip_bfloat16* __restrict__ wt2,
    float* __restrict__ bp1, float* __restrict__ bp2)
{
    const int n = blockIdx.x;
    const int u = n >> 2, g = n & 3, col = g*HU + u;
    if (blockIdx.y == 0) {
        for (int k = threadIdx.x; k < 640; k += 256) {
            float v = (k < EMBD) ? W1[k*NG + col] : ((k < 128) ? 0.f : U1[(k-128)*NG + col]);
            wt1[n*640 + k] = __float2bfloat16(v);
        }
        if (threadIdx.x == 0) bp1[n] = b1[col];
    } else {
        for (int k = threadIdx.x; k < 1024; k += 256) {
            float v = (k < HU) ? W2[k*NG + col] : U2[(k-HU)*NG + col];
            wt2[n*1024 + k] = __float2bfloat16(v);
        }
        if (threadIdx.x == 0) bp2[n] = b2[col];
    }
}

// ---------------- fused LSTM step: z = [x,h] @ wt^T + b -> gates -> c,h ----------------
// Block: 128(batch) x 128(gate-interleaved cols), 4 waves of 64x64 (4x4 MFMA frags), BK=32.
template<int KTOT, int K1P, bool GATHER>
__global__ __launch_bounds__(256) void lstm_mfma(
    const int* __restrict__ ids, const int t,
    const __hip_bfloat16* __restrict__ xsrc,   // embp (GATHER) or h1 current, stride K1P
    const __hip_bfloat16* __restrict__ hprev,  // [2048][512]
    const __hip_bfloat16* __restrict__ wt,     // [2048][KTOT]
    const float* __restrict__ bp,              // [2048] permuted bias
    float* __restrict__ cst,                   // [2048][512] fp32 cell state
    __hip_bfloat16* __restrict__ hout)         // [2048][512]
{
    constexpr int NT = KTOT / 32;
    __shared__ unsigned short As[2][128*32];
    __shared__ unsigned short Bs[2][128*32];

    const int tid  = threadIdx.x;
    const int w    = tid >> 6;
    const int lane = tid & 63;
    const int m0   = blockIdx.y * 128;
    const int n0   = blockIdx.x * 128;
    const int wm   = (w >> 1) * 64;
    const int wn   = (w & 1) * 64;

    f32x4 acc[4][4];
    #pragma unroll
    for (int mi = 0; mi < 4; ++mi)
        #pragma unroll
        for (int ni = 0; ni < 4; ++ni)
            acc[mi][ni] = (f32x4){0.f,0.f,0.f,0.f};

    const int kb   = (lane & 3) * 8;   // bf16 elems within a 32-wide row
    const int rsub = lane >> 2;        // row within a 16-row chunk

    auto stage = [&](int kt, int buf) {
        const int k0 = kt * 32;
        #pragma unroll
        for (int j = 0; j < 2; ++j) {                    // A tile: 2 x 1KB wave-chunks
            const int rowc  = w*32 + j*16 + rsub;
            const int row_g = m0 + rowc;
            const __hip_bfloat16* gp;
            if (GATHER && k0 < K1P) {
                const int id = ids[row_g*SEQ + t];
                gp = xsrc + (size_t)id*K1P + (k0 + kb);
            } else if (k0 < K1P) {
                gp = xsrc + (size_t)row_g*K1P + (k0 + kb);
            } else {
                gp = hprev + (size_t)row_g*HU + (k0 - K1P + kb);
            }
            __builtin_amdgcn_global_load_lds(AS1(gp), AS3(&As[buf][(w*32 + j*16)*32]), 16, 0, 0);
        }
        #pragma unroll
        for (int j = 0; j < 2; ++j) {                    // B tile
            const int rowc = w*32 + j*16 + rsub;
            const __hip_bfloat16* gp = wt + (size_t)(n0 + rowc)*KTOT + (k0 + kb);
            __builtin_amdgcn_global_load_lds(AS1(gp), AS3(&Bs[buf][(w*32 + j*16)*32]), 16, 0, 0);
        }
    };

    stage(0, 0);
    __syncthreads();

    for (int kt = 0; kt < NT; ++kt) {
        const int buf = kt & 1;
        if (kt + 1 < NT) stage(kt + 1, buf ^ 1);

        bf16x8 aF[4], bF[4];
        #pragma unroll
        for (int mi = 0; mi < 4; ++mi)
            aF[mi] = *(const bf16x8*)&As[buf][(wm + mi*16 + (lane & 15))*32 + (lane >> 4)*8];
        #pragma unroll
        for (int ni = 0; ni < 4; ++ni)
            bF[ni] = *(const bf16x8*)&Bs[buf][(wn + ni*16 + (lane & 15))*32 + (lane >> 4)*8];

        #pragma unroll
        for (int mi = 0; mi < 4; ++mi)
            #pragma unroll
            for (int ni = 0; ni < 4; ++ni)
                acc[mi][ni] = __builtin_amdgcn_mfma_f32_16x16x32_bf16(aF[mi], bF[ni], acc[mi][ni], 0, 0, 0);

        __syncthreads();
    }

    // Fused gate epilogue. n = u*4 + g (gate-interleaved); 4-lane group = gates i,f,g,o of one unit.
    const int gq = lane & 3;
    #pragma unroll
    for (int ni = 0; ni < 4; ++ni) {
        const int n = n0 + wn + ni*16 + (lane & 15);
        const float bv = bp[n];
        const int u = n >> 2;
        #pragma unroll
        for (int mi = 0; mi < 4; ++mi) {
            #pragma unroll
            for (int r = 0; r < 4; ++r) {
                const int bM = m0 + wm + mi*16 + (lane >> 4)*4 + r;
                const float z   = acc[mi][ni][r] + bv;
                const float act = (gq == 2) ? tanha(z) : sigm(z);
                const float act2 = __shfl_xor(act, 2);   // i<->g, f<->o
                const float pig  = act * act2;           // lane0: sig(i)*tanh(g)
                const float pig1 = __shfl_xor(pig, 1);   // lane1 <- lane0
                const float c_old = cst[bM*HU + u];      // same addr across 4-lane group
                const float cn   = fmaf(act, c_old, pig1);   // lane1: sig(f)*c + i*g
                const float tcn  = tanha(cn);
                const float tcn2 = __shfl_xor(tcn, 2);   // lane3 <- lane1
                const float hv   = act * tcn2;           // lane3: sig(o)*tanh(c)
                if (gq == 1) cst[bM*HU + u] = cn;
                else if (gq == 3) hout[bM*HU + u] = __float2bfloat16(hv);
            }
        }
    }
}

// out[b] = sigmoid(h2[b,:] @ Wd + bd)
__global__ __launch_bounds__(256) void head_k(const __hip_bfloat16* __restrict__ h2,
    const float* __restrict__ Wd, const float* __restrict__ bd, float* __restrict__ out)
{
    const int b = blockIdx.x*4 + (threadIdx.x >> 6);
    const int lane = threadIdx.x & 63;
    float s = 0.f;
    #pragma unroll
    for (int u = lane; u < HU; u += 64) s += __bfloat162float(h2[b*HU + u]) * Wd[u];
    #pragma unroll
    for (int off = 32; off > 0; off >>= 1) s += __shfl_xor(s, off);
    if (lane == 0) out[b] = 1.f/(1.f + __expf(-(s + bd[0])));
}

extern "C" void kernel_launch(void* const* d_in, const int* in_sizes, int n_in,
                              void* d_out, int out_size, void* d_ws, size_t ws_size,
                              hipStream_t stream)
{
    const int*   ids = (const int*)  d_in[0];
    const float* emb = (const float*)d_in[1];
    const float* W1  = (const float*)d_in[2];
    const float* U1  = (const float*)d_in[3];
    const float* b1  = (const float*)d_in[4];
    const float* W2  = (const float*)d_in[5];
    const float* U2  = (const float*)d_in[6];
    const float* b2  = (const float*)d_in[7];
    const float* Wd  = (const float*)d_in[8];
    const float* bd  = (const float*)d_in[9];
    float* out = (float*)d_out;

    char* p = (char*)d_ws;
    __hip_bfloat16* embp = (__hip_bfloat16*)p; p += (size_t)10000*128*2;
    __hip_bfloat16* wt1  = (__hip_bfloat16*)p; p += (size_t)2048*640*2;
    __hip_bfloat16* wt2  = (__hip_bfloat16*)p; p += (size_t)2048*1024*2;
    float* bp1 = (float*)p; p += 2048*4;
    float* bp2 = (float*)p; p += 2048*4;

    char* state = p;
    const size_t HS = (size_t)BATCH*HU;
    __hip_bfloat16* h1[2]; __hip_bfloat16* h2[2];
    h1[0] = (__hip_bfloat16*)p; p += HS*2;
    h1[1] = (__hip_bfloat16*)p; p += HS*2;
    h2[0] = (__hip_bfloat16*)p; p += HS*2;
    h2[1] = (__hip_bfloat16*)p; p += HS*2;
    float* c1 = (float*)p; p += HS*4;
    float* c2 = (float*)p; p += HS*4;

    // zero h (bf16 0 == 0x0000) and c states each call — deterministic
    hipMemsetAsync(state, 0, HS*(4*2 + 2*4), stream);

    prep_emb<<<10000*128/256, 256, 0, stream>>>(emb, embp);
    prep_wt<<<dim3(2048,2), 256, 0, stream>>>(W1,U1,b1,W2,U2,b2, wt1,wt2,bp1,bp2);

    dim3 grid(NG/128, BATCH/128);   // (16,16)
    for (int t = 0; t < SEQ; ++t) {
        const int cur = t & 1, nxt = cur ^ 1;
        lstm_mfma<640,128,true><<<grid, 256, 0, stream>>>(
            ids, t, embp, h1[cur], wt1, bp1, c1, h1[nxt]);
        lstm_mfma<1024,512,false><<<grid, 256, 0, stream>>>(
            nullptr, 0, h1[nxt], h2[cur], wt2, bp2, c2, h2[nxt]);
    }
    // final h2 written at t=79 is h2[0]
    head_k<<<BATCH/4, 256, 0, stream>>>(h2[0], Wd, bd, out);
}

// Round 3
// 3199.990 us; speedup vs baseline: 13.2264x; 2.1397x over previous
//
#include <hip/hip_runtime.h>
#include <hip/hip_bf16.h>
#include <math.h>

#define BATCH 2048
#define SEQ   80
#define EMBD  100
#define HU    512
#define NG    2048   // 4*HU

typedef short bf16x8 __attribute__((ext_vector_type(8)));
typedef float f32x4  __attribute__((ext_vector_type(4)));

#define AS1(p) ((const __attribute__((address_space(1))) void*)(p))
#define AS3(p) ((__attribute__((address_space(3))) void*)(p))

__device__ __forceinline__ float sigm(float x){ return 1.f/(1.f+__expf(-x)); }

// ---------------- prep kernels (once per call, deterministic) ----------------

// emb fp32 [10000][100] -> embp bf16 [10000][128] (cols 100..127 zero)
__global__ __launch_bounds__(256) void prep_emb(const float* __restrict__ emb,
                                                __hip_bfloat16* __restrict__ embp)
{
    int idx = blockIdx.x*256 + threadIdx.x;
    int row = idx >> 7, k = idx & 127;
    float v = (k < EMBD) ? emb[row*EMBD + k] : 0.f;
    embp[idx] = __float2bfloat16(v);
}

// Gate-interleaved transposed weights. n = u*4 + g, col_orig = g*512 + u.
__global__ __launch_bounds__(256) void prep_wt(
    const float* __restrict__ W1, const float* __restrict__ U1, const float* __restrict__ b1,
    const float* __restrict__ W2, const float* __restrict__ U2, const float* __restrict__ b2,
    __hip_bfloat16* __restrict__ wt1, __hip_bfloat16* __restrict__ wt2,
    float* __restrict__ bp1, float* __restrict__ bp2)
{
    const int n = blockIdx.x;
    const int u = n >> 2, g = n & 3, col = g*HU + u;
    if (blockIdx.y == 0) {
        for (int k = threadIdx.x; k < 640; k += 256) {
            float v = (k < EMBD) ? W1[k*NG + col] : ((k < 128) ? 0.f : U1[(k-128)*NG + col]);
            wt1[n*640 + k] = __float2bfloat16(v);
        }
        if (threadIdx.x == 0) bp1[n] = b1[col];
    } else {
        for (int k = threadIdx.x; k < 1024; k += 256) {
            float v = (k < HU) ? W2[k*NG + col] : U2[(k-HU)*NG + col];
            wt2[n*1024 + k] = __float2bfloat16(v);
        }
        if (threadIdx.x == 0) bp2[n] = b2[col];
    }
}

// ---------------- fused round kernel: L2[t=r-1] (z=0) || L1[t=r] (z=1) ----------------
// mode: 0 = both (gridDim.z==2), 1 = L1 only, 2 = L2 only.
// 128x128 tile, 512 threads (8 waves of 32x64), BK=64, dbuf LDS via global_load_lds.
// LDS chunk layout per wave: [t=k/8][row%16][8 bf16] -> 2-way-free ds_read_b128.
__global__ __launch_bounds__(512, 4) void round_k(
    const int* __restrict__ ids, const int r,
    const __hip_bfloat16* __restrict__ embp,
    const __hip_bfloat16* __restrict__ wt1, const float* __restrict__ bp1,
    const __hip_bfloat16* __restrict__ wt2, const float* __restrict__ bp2,
    const __hip_bfloat16* __restrict__ h1prev, __hip_bfloat16* __restrict__ h1out,
    const __hip_bfloat16* __restrict__ h2prev, __hip_bfloat16* __restrict__ h2out,
    float* __restrict__ c1, float* __restrict__ c2,
    const int mode)
{
    __shared__ unsigned short As[2][128*64];   // 16KB per buf
    __shared__ unsigned short Bs[2][128*64];

    const int tid  = threadIdx.x;
    const int w    = tid >> 6;
    const int lane = tid & 63;
    const int wM   = w >> 1;       // 0..3  (rows wM*32..+31)
    const int wN   = w & 1;        // 0..1  (cols wN*64..+63)
    const int m0   = blockIdx.y * 128;
    const int n0   = blockIdx.x * 128;

    const bool isL1 = (mode == 1) || (mode == 0 && blockIdx.z == 1);
    const int t     = isL1 ? r : (r - 1);
    const int KTOT  = isL1 ? 640 : 1024;
    const int K1P   = isL1 ? 128 : 512;
    const __hip_bfloat16* wt    = isL1 ? wt1 : wt2;
    const float*          bp    = isL1 ? bp1 : bp2;
    float*                cst   = isL1 ? c1  : c2;
    const __hip_bfloat16* hprev = isL1 ? h1prev : h2prev;
    const __hip_bfloat16* xs    = h1prev;          // L2's x = h1[t]
    __hip_bfloat16*       hout  = isL1 ? h1out : h2out;

    const int rA = lane & 15;      // row within this wave's 16-row staging chunk
    const int tq = lane >> 4;      // 0..3

    const int rowA = m0 + w*16 + rA;   // A staging row (batch)
    const int rowB = n0 + w*16 + rA;   // B staging row (gate-col)
    int myid = 0;
    if (isL1) myid = ids[rowA*SEQ + t];

    f32x4 acc[2][4];
    #pragma unroll
    for (int mi = 0; mi < 2; ++mi)
        #pragma unroll
        for (int ni = 0; ni < 4; ++ni)
            acc[mi][ni] = (f32x4){0.f,0.f,0.f,0.f};

    auto stage = [&](int kt, int buf){
        const int k0 = kt * 64;
        #pragma unroll
        for (int j = 0; j < 2; ++j) {
            const int kk = k0 + (j*4 + tq)*8;          // lane's global k
            // branchless region select (uniform per sweep: K1P % 32 == 0)
            const __hip_bfloat16* bx = isL1 ? (embp + (size_t)myid*128)
                                            : (xs + (size_t)rowA*HU);
            const __hip_bfloat16* gpA = (kk < K1P)
                ? (bx + kk)
                : (hprev + (size_t)rowA*HU + (kk - K1P));
            __builtin_amdgcn_global_load_lds(AS1(gpA), AS3(&As[buf][w*1024 + j*512]), 16, 0, 0);
            const __hip_bfloat16* gpB = wt + (size_t)rowB*KTOT + kk;
            __builtin_amdgcn_global_load_lds(AS1(gpB), AS3(&Bs[buf][w*1024 + j*512]), 16, 0, 0);
        }
    };

    stage(0, 0);
    __syncthreads();

    const int NT = KTOT / 64;      // 10 (L1) or 16 (L2)
    for (int kt = 0; kt < NT; ++kt) {
        const int buf = kt & 1;
        if (kt + 1 < NT) stage(kt + 1, buf ^ 1);

        #pragma unroll
        for (int s = 0; s < 2; ++s) {
            bf16x8 aF[2], bF[4];
            #pragma unroll
            for (int mi = 0; mi < 2; ++mi)
                aF[mi] = *(const bf16x8*)&As[buf][(wM*2+mi)*1024 + (s*4+tq)*128 + rA*8];
            #pragma unroll
            for (int ni = 0; ni < 4; ++ni)
                bF[ni] = *(const bf16x8*)&Bs[buf][(wN*4+ni)*1024 + (s*4+tq)*128 + rA*8];
            #pragma unroll
            for (int mi = 0; mi < 2; ++mi)
                #pragma unroll
                for (int ni = 0; ni < 4; ++ni)
                    acc[mi][ni] = __builtin_amdgcn_mfma_f32_16x16x32_bf16(aF[mi], bF[ni], acc[mi][ni], 0, 0, 0);
        }
        __syncthreads();
    }

    // Fused gate epilogue: n = u*4+g interleave, 4-lane group = {i,f,g,o} of one unit.
    const int gq = lane & 3;
    const bool isT = (gq == 2);
    #pragma unroll
    for (int ni = 0; ni < 4; ++ni) {
        const int n  = n0 + wN*64 + ni*16 + (lane & 15);
        const float bv = bp[n];
        const int u  = n >> 2;
        #pragma unroll
        for (int mi = 0; mi < 2; ++mi) {
            #pragma unroll
            for (int rr = 0; rr < 4; ++rr) {
                const int bM = m0 + wM*32 + mi*16 + (lane >> 4)*4 + rr;
                const float z  = acc[mi][ni][rr] + bv;
                const float zz = isT ? 2.f*z : z;
                const float sg = 1.f/(1.f + __expf(-zz));
                const float act = isT ? fmaf(2.f, sg, -1.f) : sg;   // tanh via sigmoid
                const float act2 = __shfl_xor(act, 2);   // i<->g, f<->o
                const float pig  = act * act2;           // gq0: sig(i)*tanh(g)
                const float pig1 = __shfl_xor(pig, 1);   // gq1 <- gq0
                const float c_old = cst[bM*HU + u];
                const float cn  = fmaf(act, c_old, pig1);            // gq1: sig(f)*c + i*g
                const float tcn = fmaf(2.f, 1.f/(1.f + __expf(-2.f*cn)), -1.f);
                const float tcn2 = __shfl_xor(tcn, 2);   // gq3 <- gq1
                const float hv  = act * tcn2;            // gq3: sig(o)*tanh(c)
                if (gq == 1) cst[bM*HU + u] = cn;
                else if (gq == 3) hout[bM*HU + u] = __float2bfloat16(hv);
            }
        }
    }
}

// out[b] = sigmoid(h2[b,:] @ Wd + bd)
__global__ __launch_bounds__(256) void head_k(const __hip_bfloat16* __restrict__ h2,
    const float* __restrict__ Wd, const float* __restrict__ bd, float* __restrict__ out)
{
    const int b = blockIdx.x*4 + (threadIdx.x >> 6);
    const int lane = threadIdx.x & 63;
    float s = 0.f;
    #pragma unroll
    for (int u = lane; u < HU; u += 64) s += __bfloat162float(h2[b*HU + u]) * Wd[u];
    #pragma unroll
    for (int off = 32; off > 0; off >>= 1) s += __shfl_xor(s, off);
    if (lane == 0) out[b] = 1.f/(1.f + __expf(-(s + bd[0])));
}

extern "C" void kernel_launch(void* const* d_in, const int* in_sizes, int n_in,
                              void* d_out, int out_size, void* d_ws, size_t ws_size,
                              hipStream_t stream)
{
    const int*   ids = (const int*)  d_in[0];
    const float* emb = (const float*)d_in[1];
    const float* W1  = (const float*)d_in[2];
    const float* U1  = (const float*)d_in[3];
    const float* b1  = (const float*)d_in[4];
    const float* W2  = (const float*)d_in[5];
    const float* U2  = (const float*)d_in[6];
    const float* b2  = (const float*)d_in[7];
    const float* Wd  = (const float*)d_in[8];
    const float* bd  = (const float*)d_in[9];
    float* out = (float*)d_out;

    char* p = (char*)d_ws;
    __hip_bfloat16* embp = (__hip_bfloat16*)p; p += (size_t)10000*128*2;
    __hip_bfloat16* wt1  = (__hip_bfloat16*)p; p += (size_t)2048*640*2;
    __hip_bfloat16* wt2  = (__hip_bfloat16*)p; p += (size_t)2048*1024*2;
    float* bp1 = (float*)p; p += 2048*4;
    float* bp2 = (float*)p; p += 2048*4;

    char* state = p;
    const size_t HS = (size_t)BATCH*HU;
    __hip_bfloat16* h1[2]; __hip_bfloat16* h2[2];
    h1[0] = (__hip_bfloat16*)p; p += HS*2;
    h1[1] = (__hip_bfloat16*)p; p += HS*2;
    h2[0] = (__hip_bfloat16*)p; p += HS*2;
    h2[1] = (__hip_bfloat16*)p; p += HS*2;
    float* c1 = (float*)p; p += HS*4;
    float* c2 = (float*)p; p += HS*4;

    hipMemsetAsync(state, 0, HS*(4*2 + 2*4), stream);

    prep_emb<<<10000*128/256, 256, 0, stream>>>(emb, embp);
    prep_wt<<<dim3(2048,2), 256, 0, stream>>>(W1,U1,b1,W2,U2,b2, wt1,wt2,bp1,bp2);

    // Round r: L1 computes t=r (r<80), L2 computes t=r-1 (r>=1), concurrently.
    for (int r = 0; r <= SEQ; ++r) {
        const int mode = (r == 0) ? 1 : ((r == SEQ) ? 2 : 0);
        dim3 g(16, 16, (mode == 0) ? 2 : 1);
        const int cur = r & 1, prv = cur ^ 1;
        round_k<<<g, 512, 0, stream>>>(ids, r, embp, wt1, bp1, wt2, bp2,
                                       h1[prv], h1[cur], h2[prv], h2[cur], c1, c2, mode);
    }
    // final h2 written at r=80 -> h2[0]
    head_k<<<BATCH/4, 256, 0, stream>>>(h2[0], Wd, bd, out);
}